// Round 16
// baseline (511.083 us; speedup 1.0000x reference)
//
#include <hip/hip_runtime.h>
#include <hip/hip_fp16.h>
#include <math.h>

#define N_NODES 50000
#define N_EDGES 640000
#define NGRAPH  256
#define NBUCK   196    // ceil(50000/256)
#define EPB     8192   // edges per hist/bin block
#define NBLK    79     // ceil(640000/8192)
#define BCAP    6144   // max edges per bucket (dataset max ~3.5K)

// k_prep block-range partition
#define PB_HIST  NBLK            // 79
#define PB_WPREP 448             // 7*16384/256
#define PB_APREP 48              // 6*2048/256
#define PB_ZERO  128             // 256*128/256
#define PREP_GRID (PB_HIST + PB_WPREP + PB_APREP + PB_ZERO)

typedef _Float16 half8_t __attribute__((ext_vector_type(8)));
typedef float floatx4 __attribute__((ext_vector_type(4)));

// ------------------------------------------------------------------
// Fused prologue: [0,79) dst-histogram | [79,527) W->fp16 swizzle |
// [527,575) aux-tile (projection folded through W) | [575,703) zero pooled.
// ------------------------------------------------------------------
__global__ __launch_bounds__(256) void k_prep(
    const int* __restrict__ dst, int* __restrict__ counts,
    const float* __restrict__ lin_w, const float* __restrict__ conv_W,
    _Float16* __restrict__ wt_g,
    const float* __restrict__ conv_asrc, const float* __restrict__ conv_adst,
    _Float16* __restrict__ aux_g,
    float* __restrict__ pooled)
{
    __shared__ int h[256];
    int b = blockIdx.x;
    if (b < PB_HIST) {
        h[threadIdx.x] = 0;
        __syncthreads();
        int e0 = b * EPB;
        int e1 = e0 + EPB; if (e1 > N_EDGES) e1 = N_EDGES;
        for (int e = e0 + threadIdx.x; e < e1; e += 256)
            atomicAdd(&h[dst[e] >> 8], 1);
        __syncthreads();
        counts[b * 256 + threadIdx.x] = h[threadIdx.x];
    } else if (b < PB_HIST + PB_WPREP) {
        int idx = (b - PB_HIST) * 256 + threadIdx.x;
        int m = idx >> 14;
        int r = idx & 16383;
        int k = r >> 7;
        int n = r & 127;
        const float* W = (m == 0) ? lin_w : conv_W + (size_t)(m - 1) * 16384;
        float v = W[(size_t)k * 128 + n];
        int slot = (k >> 3) ^ (n & 15);
        wt_g[(size_t)m * 16384 + n * 128 + slot * 8 + (k & 7)] = (_Float16)v;
    } else if (b < PB_HIST + PB_WPREP + PB_APREP) {
        int idx = (b - PB_HIST - PB_WPREP) * 256 + threadIdx.x;
        int li = idx >> 11;
        int r = idx & 2047;
        int k = r >> 4;
        int n = r & 15;
        float v = 0.f;
        if (n < 8) {
            int hh = n & 3;
            const float* a = (n < 4) ? conv_asrc : conv_adst;
            const float* Wrow = conv_W + (size_t)li * 16384 + (size_t)k * 128 + hh * 32;
            const float* av = a + (size_t)li * 128 + hh * 32;
            #pragma unroll 8
            for (int d = 0; d < 32; ++d) v += Wrow[d] * av[d];
        }
        int slot = (k >> 3) ^ n;
        aux_g[(size_t)li * 2048 + n * 128 + slot * 8 + (k & 7)] = (_Float16)v;
    } else {
        int idx = (b - PB_HIST - PB_WPREP - PB_APREP) * 256 + threadIdx.x;
        pooled[idx] = 0.f;
    }
}

// ------------------------------------------------------------------
// MFMA GEMM + folded attention projections (R13 64-row version --
// the R15 128-row variant regressed on VGPR/occupancy).
// ------------------------------------------------------------------
template <bool AF32>
__global__ __launch_bounds__(256) void k_gemm16(
    const void* __restrict__ Av, const _Float16* __restrict__ wt,
    const _Float16* __restrict__ aux, const float* __restrict__ bias,
    __half* __restrict__ C16, int M,
    float* __restrict__ a_s, float* __restrict__ a_d)
{
    __shared__ _Float16 Wt[128 * 128];
    __shared__ _Float16 Waux[16 * 128];
    int tid = threadIdx.x;
    {
        const float4* wsrc = (const float4*)wt;
        float4* wl = (float4*)Wt;
        #pragma unroll
        for (int r = 0; r < 8; ++r) wl[r * 256 + tid] = wsrc[r * 256 + tid];
        if (aux) ((float4*)Waux)[tid] = ((const float4*)aux)[tid];
    }
    __syncthreads();

    int lane = tid & 63;
    int wv = tid >> 6;
    int r0 = blockIdx.x * 64 + wv * 16;
    int cl = lane & 15;
    int ks = lane >> 4;

    int arow = r0 + cl; if (arow >= M) arow = M - 1;
    half8_t afrag[4];
    if (AF32) {
        const float* ArowF = (const float*)Av + (size_t)arow * 128 + ks * 8;
        #pragma unroll
        for (int kk = 0; kk < 4; ++kk) {
            float4 f0 = *(const float4*)(ArowF + kk * 32);
            float4 f1 = *(const float4*)(ArowF + kk * 32 + 4);
            half8_t a;
            a[0] = (_Float16)f0.x; a[1] = (_Float16)f0.y;
            a[2] = (_Float16)f0.z; a[3] = (_Float16)f0.w;
            a[4] = (_Float16)f1.x; a[5] = (_Float16)f1.y;
            a[6] = (_Float16)f1.z; a[7] = (_Float16)f1.w;
            afrag[kk] = a;
        }
    } else {
        const _Float16* Arow = (const _Float16*)Av + (size_t)arow * 128 + ks * 8;
        #pragma unroll
        for (int kk = 0; kk < 4; ++kk)
            afrag[kk] = *(const half8_t*)(Arow + kk * 32);
    }

    floatx4 acc[8];
    #pragma unroll
    for (int nt = 0; nt < 8; ++nt) acc[nt] = (floatx4){0.f, 0.f, 0.f, 0.f};

    #pragma unroll
    for (int kk = 0; kk < 4; ++kk) {
        #pragma unroll
        for (int nt = 0; nt < 8; ++nt) {
            int n = nt * 16 + cl;
            int slot = (kk * 4 + ks) ^ cl;
            half8_t bfrag = *(const half8_t*)&Wt[n * 128 + slot * 8];
            acc[nt] = __builtin_amdgcn_mfma_f32_16x16x32_f16(afrag[kk], bfrag, acc[nt], 0, 0, 0);
        }
    }

    int rg = lane >> 4;
    #pragma unroll
    for (int nt = 0; nt < 8; ++nt) {
        float bv = bias ? bias[nt * 16 + cl] : 0.f;
        #pragma unroll
        for (int j = 0; j < 4; ++j) {
            int row = r0 + rg * 4 + j;
            if (row < M)
                C16[(size_t)row * 128 + nt * 16 + cl] = __float2half(acc[nt][j] + bv);
        }
    }

    if (a_s) {
        floatx4 accP = (floatx4){0.f, 0.f, 0.f, 0.f};
        #pragma unroll
        for (int kk = 0; kk < 4; ++kk) {
            int slot = (kk * 4 + ks) ^ cl;
            half8_t bfrag = *(const half8_t*)&Waux[cl * 128 + slot * 8];
            accP = __builtin_amdgcn_mfma_f32_16x16x32_f16(afrag[kk], bfrag, accP, 0, 0, 0);
        }
        if (cl < 8) {
            float* dstp = (cl < 4) ? a_s : a_d;
            int h = cl & 3;
            #pragma unroll
            for (int j = 0; j < 4; ++j) {
                int row = r0 + rg * 4 + j;
                if (row < M) dstp[row * 4 + h] = accP[j];
            }
        }
    }
}

// ------------------------------------------------------------------
// CSR build (scan + bin + per-bucket counting sort).
// ------------------------------------------------------------------
__global__ __launch_bounds__(256) void k_scan2(const int* __restrict__ counts,
                                               int* __restrict__ base,
                                               int* __restrict__ bucketBase)
{
    __shared__ int tot[256];
    __shared__ int pref[257];
    int b = threadIdx.x;
    int s = 0;
    for (int blk = 0; blk < NBLK; ++blk) s += counts[blk * 256 + b];
    tot[b] = s;
    __syncthreads();
    if (b == 0) {
        int run = 0;
        for (int i = 0; i < 256; ++i) { pref[i] = run; run += tot[i]; }
        pref[256] = run;
    }
    __syncthreads();
    if (b <= NBUCK) bucketBase[b] = pref[b];
    int run = pref[b];
    for (int blk = 0; blk < NBLK; ++blk) {
        base[blk * 256 + b] = run;
        run += counts[blk * 256 + b];
    }
}

__global__ __launch_bounds__(256) void k_bin(const int* __restrict__ src,
                                             const int* __restrict__ dst,
                                             const float* __restrict__ ea,
                                             const int* __restrict__ base,
                                             int2* __restrict__ binned)
{
    __shared__ int cur[256];
    cur[threadIdx.x] = base[blockIdx.x * 256 + threadIdx.x];
    __syncthreads();
    int e0 = blockIdx.x * EPB;
    int e1 = e0 + EPB; if (e1 > N_EDGES) e1 = N_EDGES;
    for (int e = e0 + threadIdx.x; e < e1; e += 256) {
        int d = dst[e];
        int p = atomicAdd(&cur[d >> 8], 1);
        binned[p] = make_int2(src[e] | ((d & 255) << 16), __float_as_int(ea[e]));
    }
}

__global__ __launch_bounds__(256) void k_sortfill(const int2* __restrict__ binned,
                                                  const int* __restrict__ bucketBase,
                                                  int2* __restrict__ edata,
                                                  int* __restrict__ offs)
{
    __shared__ int bx[BCAP];
    __shared__ int by[BCAP];
    __shared__ int cnt[256];
    __shared__ int nb[256];
    int b = blockIdx.x;
    int p0 = bucketBase[b], p1 = bucketBase[b + 1];
    int m = p1 - p0;
    if (m > BCAP) m = BCAP;
    cnt[threadIdx.x] = 0;
    __syncthreads();
    for (int i = threadIdx.x; i < m; i += 256) {
        int2 v = binned[p0 + i];
        bx[i] = v.x; by[i] = v.y;
        atomicAdd(&cnt[(v.x >> 16) & 255], 1);
    }
    __syncthreads();
    if (threadIdx.x == 0) {
        int run = 0;
        for (int i = 0; i < 256; ++i) { nb[i] = run; run += cnt[i]; }
    }
    __syncthreads();
    int node = b * 256 + threadIdx.x;
    if (node < N_NODES) offs[node] = p0 + nb[threadIdx.x];
    if (b == NBUCK - 1 && threadIdx.x == 0) offs[N_NODES] = p1;
    __syncthreads();
    cnt[threadIdx.x] = nb[threadIdx.x];
    __syncthreads();
    for (int i = threadIdx.x; i < m; i += 256) {
        int dl = (bx[i] >> 16) & 255;
        int pos = atomicAdd(&cnt[dl], 1);
        edata[p0 + pos] = make_int2(bx[i] & 0xFFFF, by[i]);
    }
}

// ------------------------------------------------------------------
// Fused attention aggregation, XCD-sliced columns.
// Grid = (N/8 node-groups) x 4 lines; line = blockIdx % 4. With the
// round-robin blockIdx->XCD mapping (XCD = blockIdx % 8), XCD j only
// ever touches wx columns [32*(j%4), 32*(j%4)+32) => per-XCD working
// set 3.2 MB, fits the 4 MB L2 (was 12.8 MB => 0% L2 hit, 81 MB FETCH).
// One 64B line = 32 fp16 cols = exactly one head => ht = line.
// Wave = 2 nodes x 8 slots x 4 col-lanes x 8 cols. acc[8] keeps VGPR
// ~40 (R14's acc[32]/VGPR-60 occupancy cliff avoided).
// ------------------------------------------------------------------
__global__ __launch_bounds__(256) void k_attn6(
    const __half* __restrict__ wx16, const int2* __restrict__ edata,
    const float* __restrict__ a_s, const float* __restrict__ a_d,
    const int* __restrict__ offs, const __half* __restrict__ resid,
    __half* __restrict__ out)
{
    int line = blockIdx.x & 3;          // column line == head
    int ng = blockIdx.x >> 2;
    int lane = threadIdx.x & 63;
    int wid = threadIdx.x >> 6;
    int nh = lane >> 5;                 // node half
    int n = ng * 8 + wid * 2 + nh;
    int q = (lane >> 2) & 7;            // edge slot 0..7
    int cl = lane & 3;                  // col lane: 8 cols
    int c0 = line * 32 + cl * 8;
    int off0 = offs[n], off1 = offs[n + 1];
    int cnt = off1 - off0;
    float adn = a_d[n * 4 + line];
    const _Float16* wx = (const _Float16*)wx16;

    float den = 0.f;
    float acc[8];
    #pragma unroll
    for (int k = 0; k < 8; ++k) acc[k] = 0.f;

    #define STEP(jj) {                                                         \
        int2 ed = edata[off0 + (jj)];                                          \
        float t = a_s[ed.x * 4 + line] + adn;                                  \
        t = (t > 0.f ? t : 0.2f * t) * __int_as_float(ed.y);                   \
        float w = __expf(fminf(t, 80.f));                                      \
        den += w;                                                              \
        half8_t g = *(const half8_t*)&wx[(size_t)ed.x * 128 + c0];             \
        acc[0] += w * (float)g[0]; acc[1] += w * (float)g[1];                  \
        acc[2] += w * (float)g[2]; acc[3] += w * (float)g[3];                  \
        acc[4] += w * (float)g[4]; acc[5] += w * (float)g[5];                  \
        acc[6] += w * (float)g[6]; acc[7] += w * (float)g[7]; }

    int j = q;
    for (; j + 8 < cnt; j += 16) { STEP(j); STEP(j + 8); }
    if (j < cnt) STEP(j);
    #undef STEP

    // reduce over slots (lane bits 2,3,4); cl (bits 0-1), nh (bit 5) fixed
    den += __shfl_xor(den, 4);
    den += __shfl_xor(den, 8);
    den += __shfl_xor(den, 16);
    #pragma unroll
    for (int k = 0; k < 8; ++k) {
        acc[k] += __shfl_xor(acc[k], 4);
        acc[k] += __shfl_xor(acc[k], 8);
        acc[k] += __shfl_xor(acc[k], 16);
    }

    if (q == 0) {
        float inv = 1.f / (den + 1e-16f);
        half8_t rv;
        if (resid) rv = *(const half8_t*)((const _Float16*)resid + (size_t)n * 128 + c0);
        half8_t o;
        #pragma unroll
        for (int k = 0; k < 8; ++k) {
            float r = acc[k] * inv;
            r = r > 0.f ? r : (__expf(r) - 1.f);   // ELU, cheap form
            if (resid) r += (float)rv[k];
            o[k] = (_Float16)r;
        }
        *(half8_t*)((_Float16*)out + (size_t)n * 128 + c0) = o;
    }
}

// ------------------------------------------------------------------
// Pool: chunked partial sums + atomic flush at segment boundaries.
// ------------------------------------------------------------------
__global__ __launch_bounds__(256) void k_pool2(
    const __half* __restrict__ h, const int* __restrict__ batch,
    float* __restrict__ pooled)
{
    int c = threadIdx.x & 127;
    int hf = threadIdx.x >> 7;
    int n0 = blockIdx.x * 64 + hf * 32;
    if (n0 >= N_NODES) return;
    int nend = n0 + 32; if (nend > N_NODES) nend = N_NODES;

    int g = batch[n0];
    float acc = 0.f;
    for (int n = n0; n < nend; ++n) {
        int bg = batch[n];
        if (bg != g) { atomicAdd(&pooled[g * 128 + c], acc); acc = 0.f; g = bg; }
        acc += __half2float(h[(size_t)n * 128 + c]);
    }
    atomicAdd(&pooled[g * 128 + c], acc);
}

// ------------------------------------------------------------------
// Linear + BatchNorm (+relu)
// ------------------------------------------------------------------
template <int K, int OC>
__global__ __launch_bounds__(256) void k_mlp(
    const float* __restrict__ in, const float* __restrict__ w,
    const float* __restrict__ b, const float* __restrict__ gam,
    const float* __restrict__ bet, float* __restrict__ out, int do_relu)
{
    __shared__ float2 red[256];
    int c = blockIdx.x, g = threadIdx.x;
    float val = b[c];
    #pragma unroll 8
    for (int k = 0; k < K; ++k) val += in[g * K + k] * w[k * OC + c];
    red[g] = make_float2(val, val * val);
    __syncthreads();
    for (int s = 128; s > 0; s >>= 1) {
        if (g < s) { red[g].x += red[g + s].x; red[g].y += red[g + s].y; }
        __syncthreads();
    }
    float mean = red[0].x * (1.f / 256.f);
    float var = red[0].y * (1.f / 256.f) - mean * mean;
    float y = (val - mean) * rsqrtf(var + 1e-5f) * gam[c] + bet[c];
    if (do_relu) y = fmaxf(y, 0.f);
    out[g * OC + c] = y;
}

// ------------------------------------------------------------------
extern "C" void kernel_launch(void* const* d_in, const int* in_sizes, int n_in,
                              void* d_out, int out_size, void* d_ws, size_t ws_size,
                              hipStream_t stream)
{
    const float* x         = (const float*)d_in[0];
    const float* edge_attr = (const float*)d_in[1];
    const float* lin_w     = (const float*)d_in[2];
    const float* lin_b     = (const float*)d_in[3];
    const float* conv_W    = (const float*)d_in[4];
    const float* conv_asrc = (const float*)d_in[5];
    const float* conv_adst = (const float*)d_in[6];
    const float* fc_w1 = (const float*)d_in[7];
    const float* fc_b1 = (const float*)d_in[8];
    const float* bn_g1 = (const float*)d_in[9];
    const float* bn_b1 = (const float*)d_in[10];
    const float* fc_w2 = (const float*)d_in[11];
    const float* fc_b2 = (const float*)d_in[12];
    const float* bn_g2 = (const float*)d_in[13];
    const float* bn_b2 = (const float*)d_in[14];
    const float* fc_w3 = (const float*)d_in[15];
    const float* fc_b3 = (const float*)d_in[16];
    const float* bn_g3 = (const float*)d_in[17];
    const float* bn_b3 = (const float*)d_in[18];
    const int* edge_index = (const int*)d_in[19];
    const int* batch      = (const int*)d_in[20];
    const int* srcp = edge_index;
    const int* dstp = edge_index + N_EDGES;
    float* out = (float*)d_out;

    char* ws = (char*)d_ws;
    __half* h_cur = (__half*)ws; ws += (size_t)N_NODES * 128 * 2;
    __half* h_tmp = (__half*)ws; ws += (size_t)N_NODES * 128 * 2;
    __half* wx16  = (__half*)ws; ws += (size_t)N_NODES * 128 * 2;
    float* a_s   = (float*)ws;  ws += (size_t)N_NODES * 4 * 4;
    float* a_d   = (float*)ws;  ws += (size_t)N_NODES * 4 * 4;
    float* pooled= (float*)ws;  ws += (size_t)NGRAPH * 128 * 4;
    float* z1    = (float*)ws;  ws += (size_t)NGRAPH * 64 * 4;
    float* z2    = (float*)ws;  ws += (size_t)NGRAPH * 32 * 4;
    int* offs    = (int*)ws;    ws += (size_t)(N_NODES + 4) * 4;
    int2* edata  = (int2*)ws;   ws += (size_t)N_EDGES * 8;
    int2* binned = (int2*)ws;   ws += (size_t)N_EDGES * 8;
    int* counts  = (int*)ws;    ws += (size_t)NBLK * 256 * 4;
    int* base    = (int*)ws;    ws += (size_t)NBLK * 256 * 4;
    int* bucketBase = (int*)ws; ws += 256 * 4;
    _Float16* wt_g = (_Float16*)ws; ws += (size_t)7 * 16384 * 2;
    _Float16* wt_aux = (_Float16*)ws; ws += (size_t)6 * 2048 * 2;

    // --- fused prologue + CSR build ---
    k_prep<<<PREP_GRID, 256, 0, stream>>>(dstp, counts, lin_w, conv_W, wt_g,
                                          conv_asrc, conv_adst, wt_aux, pooled);
    k_scan2<<<1, 256, 0, stream>>>(counts, base, bucketBase);
    k_bin<<<NBLK, 256, 0, stream>>>(srcp, dstp, edge_attr, base, binned);
    k_sortfill<<<NBUCK, 256, 0, stream>>>(binned, bucketBase, edata, offs);

    const int GGRID = (N_NODES + 63) / 64;        // 782
    const int AGRID = ((N_NODES + 7) / 8) * 4;    // 25000 (node-groups x 4 lines)

    // --- input linear (reads fp32 x directly) ---
    k_gemm16<true><<<GGRID, 256, 0, stream>>>(x, wt_g, nullptr, lin_b, h_cur,
                                              N_NODES, nullptr, nullptr);

    // --- 3 residual scatter convs, 2 inner layers each ---
    for (int i = 0; i < 3; ++i) {
        const _Float16* W0 = wt_g + (size_t)(1 + i * 2 + 0) * 16384;
        const _Float16* W1 = wt_g + (size_t)(1 + i * 2 + 1) * 16384;
        const _Float16* X0 = wt_aux + (size_t)(i * 2 + 0) * 2048;
        const _Float16* X1 = wt_aux + (size_t)(i * 2 + 1) * 2048;

        k_gemm16<false><<<GGRID, 256, 0, stream>>>(h_cur, W0, X0, nullptr, wx16,
                                                   N_NODES, a_s, a_d);
        k_attn6<<<AGRID, 256, 0, stream>>>(wx16, edata, a_s, a_d,
                                           offs, nullptr, h_tmp);

        k_gemm16<false><<<GGRID, 256, 0, stream>>>(h_tmp, W1, X1, nullptr, wx16,
                                                   N_NODES, a_s, a_d);
        k_attn6<<<AGRID, 256, 0, stream>>>(wx16, edata, a_s, a_d,
                                           offs, h_cur, h_cur);
    }

    // --- pool + MLP head ---
    k_pool2<<<(N_NODES + 63) / 64, 256, 0, stream>>>(h_cur, batch, pooled);
    k_mlp<128, 64><<<64, 256, 0, stream>>>(pooled, fc_w1, fc_b1, bn_g1, bn_b1, z1, 1);
    k_mlp<64, 32><<<32, 256, 0, stream>>>(z1, fc_w2, fc_b2, bn_g2, bn_b2, z2, 1);
    k_mlp<32, 10><<<10, 256, 0, stream>>>(z2, fc_w3, fc_b3, bn_g3, bn_b3, out, 0);
}

// Round 17
// 371.706 us; speedup vs baseline: 1.3750x; 1.3750x over previous
//
#include <hip/hip_runtime.h>
#include <hip/hip_fp16.h>
#include <math.h>

#define N_NODES 50000
#define N_EDGES 640000
#define NGRAPH  256
#define NBUCK   196    // ceil(50000/256)
#define EPB     8192   // edges per hist/bin block
#define NBLK    79     // ceil(640000/8192)
#define BCAP    6144   // max edges per bucket (dataset max ~3.5K)

// k_prep block-range partition
#define PB_HIST  NBLK            // 79
#define PB_WPREP 448             // 7*16384/256
#define PB_APREP 48              // 6*2048/256
#define PB_ZERO  128             // 256*128/256
#define PREP_GRID (PB_HIST + PB_WPREP + PB_APREP + PB_ZERO)

typedef _Float16 half8_t __attribute__((ext_vector_type(8)));
typedef float floatx4 __attribute__((ext_vector_type(4)));

// ------------------------------------------------------------------
// Fused prologue: [0,79) dst-histogram | [79,527) W->fp16 swizzle |
// [527,575) aux-tile (projection folded through W) | [575,703) zero pooled.
// ------------------------------------------------------------------
__global__ __launch_bounds__(256) void k_prep(
    const int* __restrict__ dst, int* __restrict__ counts,
    const float* __restrict__ lin_w, const float* __restrict__ conv_W,
    _Float16* __restrict__ wt_g,
    const float* __restrict__ conv_asrc, const float* __restrict__ conv_adst,
    _Float16* __restrict__ aux_g,
    float* __restrict__ pooled)
{
    __shared__ int h[256];
    int b = blockIdx.x;
    if (b < PB_HIST) {
        h[threadIdx.x] = 0;
        __syncthreads();
        int e0 = b * EPB;
        int e1 = e0 + EPB; if (e1 > N_EDGES) e1 = N_EDGES;
        for (int e = e0 + threadIdx.x; e < e1; e += 256)
            atomicAdd(&h[dst[e] >> 8], 1);
        __syncthreads();
        counts[b * 256 + threadIdx.x] = h[threadIdx.x];
    } else if (b < PB_HIST + PB_WPREP) {
        int idx = (b - PB_HIST) * 256 + threadIdx.x;
        int m = idx >> 14;
        int r = idx & 16383;
        int k = r >> 7;
        int n = r & 127;
        const float* W = (m == 0) ? lin_w : conv_W + (size_t)(m - 1) * 16384;
        float v = W[(size_t)k * 128 + n];
        int slot = (k >> 3) ^ (n & 15);
        wt_g[(size_t)m * 16384 + n * 128 + slot * 8 + (k & 7)] = (_Float16)v;
    } else if (b < PB_HIST + PB_WPREP + PB_APREP) {
        int idx = (b - PB_HIST - PB_WPREP) * 256 + threadIdx.x;
        int li = idx >> 11;
        int r = idx & 2047;
        int k = r >> 4;
        int n = r & 15;
        float v = 0.f;
        if (n < 8) {
            int hh = n & 3;
            const float* a = (n < 4) ? conv_asrc : conv_adst;
            const float* Wrow = conv_W + (size_t)li * 16384 + (size_t)k * 128 + hh * 32;
            const float* av = a + (size_t)li * 128 + hh * 32;
            #pragma unroll 8
            for (int d = 0; d < 32; ++d) v += Wrow[d] * av[d];
        }
        int slot = (k >> 3) ^ n;
        aux_g[(size_t)li * 2048 + n * 128 + slot * 8 + (k & 7)] = (_Float16)v;
    } else {
        int idx = (b - PB_HIST - PB_WPREP - PB_APREP) * 256 + threadIdx.x;
        pooled[idx] = 0.f;
    }
}

// ------------------------------------------------------------------
// MFMA GEMM + folded attention projections (1 aux MFMA tile).
// AF32: A is fp32 (input linear) -- converted in-register.
// 64 rows/block, 4 waves: best-measured configuration (R13).
// ------------------------------------------------------------------
template <bool AF32>
__global__ __launch_bounds__(256) void k_gemm16(
    const void* __restrict__ Av, const _Float16* __restrict__ wt,
    const _Float16* __restrict__ aux, const float* __restrict__ bias,
    __half* __restrict__ C16, int M,
    float* __restrict__ a_s, float* __restrict__ a_d)
{
    __shared__ _Float16 Wt[128 * 128];
    __shared__ _Float16 Waux[16 * 128];
    int tid = threadIdx.x;
    {
        const float4* wsrc = (const float4*)wt;
        float4* wl = (float4*)Wt;
        #pragma unroll
        for (int r = 0; r < 8; ++r) wl[r * 256 + tid] = wsrc[r * 256 + tid];
        if (aux) ((float4*)Waux)[tid] = ((const float4*)aux)[tid];
    }
    __syncthreads();

    int lane = tid & 63;
    int wv = tid >> 6;
    int r0 = blockIdx.x * 64 + wv * 16;
    int cl = lane & 15;
    int ks = lane >> 4;

    int arow = r0 + cl; if (arow >= M) arow = M - 1;
    half8_t afrag[4];
    if (AF32) {
        const float* ArowF = (const float*)Av + (size_t)arow * 128 + ks * 8;
        #pragma unroll
        for (int kk = 0; kk < 4; ++kk) {
            float4 f0 = *(const float4*)(ArowF + kk * 32);
            float4 f1 = *(const float4*)(ArowF + kk * 32 + 4);
            half8_t a;
            a[0] = (_Float16)f0.x; a[1] = (_Float16)f0.y;
            a[2] = (_Float16)f0.z; a[3] = (_Float16)f0.w;
            a[4] = (_Float16)f1.x; a[5] = (_Float16)f1.y;
            a[6] = (_Float16)f1.z; a[7] = (_Float16)f1.w;
            afrag[kk] = a;
        }
    } else {
        const _Float16* Arow = (const _Float16*)Av + (size_t)arow * 128 + ks * 8;
        #pragma unroll
        for (int kk = 0; kk < 4; ++kk)
            afrag[kk] = *(const half8_t*)(Arow + kk * 32);
    }

    floatx4 acc[8];
    #pragma unroll
    for (int nt = 0; nt < 8; ++nt) acc[nt] = (floatx4){0.f, 0.f, 0.f, 0.f};

    #pragma unroll
    for (int kk = 0; kk < 4; ++kk) {
        #pragma unroll
        for (int nt = 0; nt < 8; ++nt) {
            int n = nt * 16 + cl;
            int slot = (kk * 4 + ks) ^ cl;
            half8_t bfrag = *(const half8_t*)&Wt[n * 128 + slot * 8];
            acc[nt] = __builtin_amdgcn_mfma_f32_16x16x32_f16(afrag[kk], bfrag, acc[nt], 0, 0, 0);
        }
    }

    int rg = lane >> 4;
    #pragma unroll
    for (int nt = 0; nt < 8; ++nt) {
        float bv = bias ? bias[nt * 16 + cl] : 0.f;
        #pragma unroll
        for (int j = 0; j < 4; ++j) {
            int row = r0 + rg * 4 + j;
            if (row < M)
                C16[(size_t)row * 128 + nt * 16 + cl] = __float2half(acc[nt][j] + bv);
        }
    }

    if (a_s) {
        floatx4 accP = (floatx4){0.f, 0.f, 0.f, 0.f};
        #pragma unroll
        for (int kk = 0; kk < 4; ++kk) {
            int slot = (kk * 4 + ks) ^ cl;
            half8_t bfrag = *(const half8_t*)&Waux[cl * 128 + slot * 8];
            accP = __builtin_amdgcn_mfma_f32_16x16x32_f16(afrag[kk], bfrag, accP, 0, 0, 0);
        }
        if (cl < 8) {
            float* dstp = (cl < 4) ? a_s : a_d;
            int h = cl & 3;
            #pragma unroll
            for (int j = 0; j < 4; ++j) {
                int row = r0 + rg * 4 + j;
                if (row < M) dstp[row * 4 + h] = accP[j];
            }
        }
    }
}

// ------------------------------------------------------------------
// CSR build (scan + bin + per-bucket counting sort).
// ------------------------------------------------------------------
__global__ __launch_bounds__(256) void k_scan2(const int* __restrict__ counts,
                                               int* __restrict__ base,
                                               int* __restrict__ bucketBase)
{
    __shared__ int tot[256];
    __shared__ int pref[257];
    int b = threadIdx.x;
    int s = 0;
    for (int blk = 0; blk < NBLK; ++blk) s += counts[blk * 256 + b];
    tot[b] = s;
    __syncthreads();
    if (b == 0) {
        int run = 0;
        for (int i = 0; i < 256; ++i) { pref[i] = run; run += tot[i]; }
        pref[256] = run;
    }
    __syncthreads();
    if (b <= NBUCK) bucketBase[b] = pref[b];
    int run = pref[b];
    for (int blk = 0; blk < NBLK; ++blk) {
        base[blk * 256 + b] = run;
        run += counts[blk * 256 + b];
    }
}

__global__ __launch_bounds__(256) void k_bin(const int* __restrict__ src,
                                             const int* __restrict__ dst,
                                             const float* __restrict__ ea,
                                             const int* __restrict__ base,
                                             int2* __restrict__ binned)
{
    __shared__ int cur[256];
    cur[threadIdx.x] = base[blockIdx.x * 256 + threadIdx.x];
    __syncthreads();
    int e0 = blockIdx.x * EPB;
    int e1 = e0 + EPB; if (e1 > N_EDGES) e1 = N_EDGES;
    for (int e = e0 + threadIdx.x; e < e1; e += 256) {
        int d = dst[e];
        int p = atomicAdd(&cur[d >> 8], 1);
        binned[p] = make_int2(src[e] | ((d & 255) << 16), __float_as_int(ea[e]));
    }
}

__global__ __launch_bounds__(256) void k_sortfill(const int2* __restrict__ binned,
                                                  const int* __restrict__ bucketBase,
                                                  int2* __restrict__ edata,
                                                  int* __restrict__ offs)
{
    __shared__ int bx[BCAP];
    __shared__ int by[BCAP];
    __shared__ int cnt[256];
    __shared__ int nb[256];
    int b = blockIdx.x;
    int p0 = bucketBase[b], p1 = bucketBase[b + 1];
    int m = p1 - p0;
    if (m > BCAP) m = BCAP;
    cnt[threadIdx.x] = 0;
    __syncthreads();
    for (int i = threadIdx.x; i < m; i += 256) {
        int2 v = binned[p0 + i];
        bx[i] = v.x; by[i] = v.y;
        atomicAdd(&cnt[(v.x >> 16) & 255], 1);
    }
    __syncthreads();
    if (threadIdx.x == 0) {
        int run = 0;
        for (int i = 0; i < 256; ++i) { nb[i] = run; run += cnt[i]; }
    }
    __syncthreads();
    int node = b * 256 + threadIdx.x;
    if (node < N_NODES) offs[node] = p0 + nb[threadIdx.x];
    if (b == NBUCK - 1 && threadIdx.x == 0) offs[N_NODES] = p1;
    __syncthreads();
    cnt[threadIdx.x] = nb[threadIdx.x];
    __syncthreads();
    for (int i = threadIdx.x; i < m; i += 256) {
        int dl = (bx[i] >> 16) & 255;
        int pos = atomicAdd(&cnt[dl], 1);
        edata[p0 + pos] = make_int2(bx[i] & 0xFFFF, by[i]);
    }
}

// ------------------------------------------------------------------
// Fused attention aggregation, 2 nodes per wave (R12/R13 layout —
// the best-measured shape; R14 8-slot and R16 XCD-sliced variants
// both regressed on occupancy / locality).
// ------------------------------------------------------------------
__global__ __launch_bounds__(256) void k_attn4(
    const __half* __restrict__ wx16, const int2* __restrict__ edata,
    const float* __restrict__ a_s, const float* __restrict__ a_d,
    const int* __restrict__ offs, const __half* __restrict__ resid,
    __half* __restrict__ out)
{
    int lane = threadIdx.x & 63;
    int wid = threadIdx.x >> 6;
    int nh = lane >> 5;
    int n = blockIdx.x * 8 + wid * 2 + nh;
    int q = (lane >> 3) & 3;
    int cl = lane & 7;
    int c0 = cl * 16;
    int ht = cl >> 1;
    int off0 = offs[n], off1 = offs[n + 1];
    int cnt = off1 - off0;
    float adn = a_d[n * 4 + ht];
    const _Float16* wx = (const _Float16*)wx16;

    float den = 0.f;
    float acc[16];
    #pragma unroll
    for (int k = 0; k < 16; ++k) acc[k] = 0.f;

    #define STEP(jj) {                                                         \
        int2 ed = edata[off0 + (jj)];                                          \
        float t = a_s[ed.x * 4 + ht] + adn;                                    \
        t = (t > 0.f ? t : 0.2f * t) * __int_as_float(ed.y);                   \
        float w = __expf(fminf(t, 80.f));                                      \
        den += w;                                                              \
        const _Float16* rp = &wx[(size_t)ed.x * 128 + c0];                     \
        half8_t g0 = *(const half8_t*)rp;                                      \
        half8_t g1 = *(const half8_t*)(rp + 8);                                \
        acc[0]  += w * (float)g0[0]; acc[1]  += w * (float)g0[1];              \
        acc[2]  += w * (float)g0[2]; acc[3]  += w * (float)g0[3];              \
        acc[4]  += w * (float)g0[4]; acc[5]  += w * (float)g0[5];              \
        acc[6]  += w * (float)g0[6]; acc[7]  += w * (float)g0[7];              \
        acc[8]  += w * (float)g1[0]; acc[9]  += w * (float)g1[1];              \
        acc[10] += w * (float)g1[2]; acc[11] += w * (float)g1[3];              \
        acc[12] += w * (float)g1[4]; acc[13] += w * (float)g1[5];              \
        acc[14] += w * (float)g1[6]; acc[15] += w * (float)g1[7]; }

    int j = q;
    for (; j + 4 < cnt; j += 8) { STEP(j); STEP(j + 4); }
    if (j < cnt) STEP(j);
    #undef STEP

    den += __shfl_xor(den, 8);
    den += __shfl_xor(den, 16);
    #pragma unroll
    for (int k = 0; k < 16; ++k) {
        acc[k] += __shfl_xor(acc[k], 8);
        acc[k] += __shfl_xor(acc[k], 16);
    }

    if (q == 0) {
        float inv = 1.f / (den + 1e-16f);
        const _Float16* rvp = resid ? (const _Float16*)resid + (size_t)n * 128 + c0 : nullptr;
        half8_t rv0, rv1;
        if (resid) { rv0 = *(const half8_t*)rvp; rv1 = *(const half8_t*)(rvp + 8); }
        half8_t o0, o1;
        #pragma unroll
        for (int k = 0; k < 8; ++k) {
            float r = acc[k] * inv;
            r = r > 0.f ? r : (__expf(r) - 1.f);
            if (resid) r += (float)rv0[k];
            o0[k] = (_Float16)r;
        }
        #pragma unroll
        for (int k = 0; k < 8; ++k) {
            float r = acc[8 + k] * inv;
            r = r > 0.f ? r : (__expf(r) - 1.f);
            if (resid) r += (float)rv1[k];
            o1[k] = (_Float16)r;
        }
        _Float16* op = (_Float16*)out + (size_t)n * 128 + c0;
        *(half8_t*)op = o0;
        *(half8_t*)(op + 8) = o1;
    }
}

// ------------------------------------------------------------------
// Pool: chunked partial sums + atomic flush at segment boundaries.
// ------------------------------------------------------------------
__global__ __launch_bounds__(256) void k_pool2(
    const __half* __restrict__ h, const int* __restrict__ batch,
    float* __restrict__ pooled)
{
    int c = threadIdx.x & 127;
    int hf = threadIdx.x >> 7;
    int n0 = blockIdx.x * 64 + hf * 32;
    if (n0 >= N_NODES) return;
    int nend = n0 + 32; if (nend > N_NODES) nend = N_NODES;

    int g = batch[n0];
    float acc = 0.f;
    for (int n = n0; n < nend; ++n) {
        int bg = batch[n];
        if (bg != g) { atomicAdd(&pooled[g * 128 + c], acc); acc = 0.f; g = bg; }
        acc += __half2float(h[(size_t)n * 128 + c]);
    }
    atomicAdd(&pooled[g * 128 + c], acc);
}

// ------------------------------------------------------------------
// Linear + BatchNorm (+relu)
// ------------------------------------------------------------------
template <int K, int OC>
__global__ __launch_bounds__(256) void k_mlp(
    const float* __restrict__ in, const float* __restrict__ w,
    const float* __restrict__ b, const float* __restrict__ gam,
    const float* __restrict__ bet, float* __restrict__ out, int do_relu)
{
    __shared__ float2 red[256];
    int c = blockIdx.x, g = threadIdx.x;
    float val = b[c];
    #pragma unroll 8
    for (int k = 0; k < K; ++k) val += in[g * K + k] * w[k * OC + c];
    red[g] = make_float2(val, val * val);
    __syncthreads();
    for (int s = 128; s > 0; s >>= 1) {
        if (g < s) { red[g].x += red[g + s].x; red[g].y += red[g + s].y; }
        __syncthreads();
    }
    float mean = red[0].x * (1.f / 256.f);
    float var = red[0].y * (1.f / 256.f) - mean * mean;
    float y = (val - mean) * rsqrtf(var + 1e-5f) * gam[c] + bet[c];
    if (do_relu) y = fmaxf(y, 0.f);
    out[g * OC + c] = y;
}

// ------------------------------------------------------------------
extern "C" void kernel_launch(void* const* d_in, const int* in_sizes, int n_in,
                              void* d_out, int out_size, void* d_ws, size_t ws_size,
                              hipStream_t stream)
{
    const float* x         = (const float*)d_in[0];
    const float* edge_attr = (const float*)d_in[1];
    const float* lin_w     = (const float*)d_in[2];
    const float* lin_b     = (const float*)d_in[3];
    const float* conv_W    = (const float*)d_in[4];
    const float* conv_asrc = (const float*)d_in[5];
    const float* conv_adst = (const float*)d_in[6];
    const float* fc_w1 = (const float*)d_in[7];
    const float* fc_b1 = (const float*)d_in[8];
    const float* bn_g1 = (const float*)d_in[9];
    const float* bn_b1 = (const float*)d_in[10];
    const float* fc_w2 = (const float*)d_in[11];
    const float* fc_b2 = (const float*)d_in[12];
    const float* bn_g2 = (const float*)d_in[13];
    const float* bn_b2 = (const float*)d_in[14];
    const float* fc_w3 = (const float*)d_in[15];
    const float* fc_b3 = (const float*)d_in[16];
    const float* bn_g3 = (const float*)d_in[17];
    const float* bn_b3 = (const float*)d_in[18];
    const int* edge_index = (const int*)d_in[19];
    const int* batch      = (const int*)d_in[20];
    const int* srcp = edge_index;
    const int* dstp = edge_index + N_EDGES;
    float* out = (float*)d_out;

    char* ws = (char*)d_ws;
    __half* h_cur = (__half*)ws; ws += (size_t)N_NODES * 128 * 2;
    __half* h_tmp = (__half*)ws; ws += (size_t)N_NODES * 128 * 2;
    __half* wx16  = (__half*)ws; ws += (size_t)N_NODES * 128 * 2;
    float* a_s   = (float*)ws;  ws += (size_t)N_NODES * 4 * 4;
    float* a_d   = (float*)ws;  ws += (size_t)N_NODES * 4 * 4;
    float* pooled= (float*)ws;  ws += (size_t)NGRAPH * 128 * 4;
    float* z1    = (float*)ws;  ws += (size_t)NGRAPH * 64 * 4;
    float* z2    = (float*)ws;  ws += (size_t)NGRAPH * 32 * 4;
    int* offs    = (int*)ws;    ws += (size_t)(N_NODES + 4) * 4;
    int2* edata  = (int2*)ws;   ws += (size_t)N_EDGES * 8;
    int2* binned = (int2*)ws;   ws += (size_t)N_EDGES * 8;
    int* counts  = (int*)ws;    ws += (size_t)NBLK * 256 * 4;
    int* base    = (int*)ws;    ws += (size_t)NBLK * 256 * 4;
    int* bucketBase = (int*)ws; ws += 256 * 4;
    _Float16* wt_g = (_Float16*)ws; ws += (size_t)7 * 16384 * 2;
    _Float16* wt_aux = (_Float16*)ws; ws += (size_t)6 * 2048 * 2;

    // --- fused prologue + CSR build ---
    k_prep<<<PREP_GRID, 256, 0, stream>>>(dstp, counts, lin_w, conv_W, wt_g,
                                          conv_asrc, conv_adst, wt_aux, pooled);
    k_scan2<<<1, 256, 0, stream>>>(counts, base, bucketBase);
    k_bin<<<NBLK, 256, 0, stream>>>(srcp, dstp, edge_attr, base, binned);
    k_sortfill<<<NBUCK, 256, 0, stream>>>(binned, bucketBase, edata, offs);

    const int GGRID = (N_NODES + 63) / 64;
    const int AGRID = (N_NODES + 7) / 8;

    // --- input linear (reads fp32 x directly) ---
    k_gemm16<true><<<GGRID, 256, 0, stream>>>(x, wt_g, nullptr, lin_b, h_cur,
                                              N_NODES, nullptr, nullptr);

    // --- 3 residual scatter convs, 2 inner layers each ---
    for (int i = 0; i < 3; ++i) {
        const _Float16* W0 = wt_g + (size_t)(1 + i * 2 + 0) * 16384;
        const _Float16* W1 = wt_g + (size_t)(1 + i * 2 + 1) * 16384;
        const _Float16* X0 = wt_aux + (size_t)(i * 2 + 0) * 2048;
        const _Float16* X1 = wt_aux + (size_t)(i * 2 + 1) * 2048;

        k_gemm16<false><<<GGRID, 256, 0, stream>>>(h_cur, W0, X0, nullptr, wx16,
                                                   N_NODES, a_s, a_d);
        k_attn4<<<AGRID, 256, 0, stream>>>(wx16, edata, a_s, a_d,
                                           offs, nullptr, h_tmp);

        k_gemm16<false><<<GGRID, 256, 0, stream>>>(h_tmp, W1, X1, nullptr, wx16,
                                                   N_NODES, a_s, a_d);
        k_attn4<<<AGRID, 256, 0, stream>>>(wx16, edata, a_s, a_d,
                                           offs, h_cur, h_cur);
    }

    // --- pool + MLP head ---
    k_pool2<<<(N_NODES + 63) / 64, 256, 0, stream>>>(h_cur, batch, pooled);
    k_mlp<128, 64><<<64, 256, 0, stream>>>(pooled, fc_w1, fc_b1, bn_g1, bn_b1, z1, 1);
    k_mlp<64, 32><<<32, 256, 0, stream>>>(z1, fc_w2, fc_b2, bn_g2, bn_b2, z2, 1);
    k_mlp<32, 10><<<10, 256, 0, stream>>>(z2, fc_w3, fc_b3, bn_g3, bn_b3, out, 0);
}